// Round 3
// baseline (204.040 us; speedup 1.0000x reference)
//
#include <hip/hip_runtime.h>
#include <hip/hip_cooperative_groups.h>

namespace cg = cooperative_groups;

// FDN reverb == 8-tap sparse FIR + 50/50 mix + global max-abs normalize.
// Fully fused: one cooperative kernel, grid-wide sync for the global max.
#define T_LEN 8388608
#define NTAPS 8
#define NBLK  512                 // 2 blocks/CU, all co-resident (LDS-limited)
#define CHUNK (T_LEN / NBLK)      // 16384 outputs per block
#define HALO  3840                // >= max delay (3825), multiple of 4
#define LDSF  (HALO + CHUNK)      // 20224 floats = 80896 B -> exactly 2 blocks/CU

#define D0 1425
#define D1 1780
#define D2 1972
#define D3 2097
#define D4 2558
#define D5 2961
#define D6 3508
#define D7 3825

__global__ __launch_bounds__(256, 2) void fdn_fused(
    const float* __restrict__ x, const float* __restrict__ g,
    const float* __restrict__ Q, float* __restrict__ out,
    float* __restrict__ wsf) {
    __shared__ __align__(16) float smem[LDSF];
    __shared__ float csh[NTAPS];
    __shared__ float wmax[4];
    __shared__ float sinv;

    const int tid = threadIdx.x;
    const int blk = blockIdx.x;

    // combined[n] = g[n] * sum_j Q[j,n]
    if (tid < NTAPS) {
        float s = 0.f;
#pragma unroll
        for (int j = 0; j < NTAPS; ++j) s += Q[j * NTAPS + tid];
        csh[tid] = s * g[tid];
    }

    // Stage [blk*CHUNK - HALO, blk*CHUNK + CHUNK) into LDS; zeros before t=0.
    const long gs = (long)blk * CHUNK - HALO;     // float index; *4B is 16B aligned
    for (int v4 = tid; v4 < LDSF / 4; v4 += 256) {
        long ga = gs + (long)v4 * 4;
        float4 val = make_float4(0.f, 0.f, 0.f, 0.f);
        if (ga >= 0) val = *(const float4*)(x + ga);
        *(float4*)(smem + v4 * 4) = val;
    }
    __syncthreads();

    const float c0 = csh[0], c1 = csh[1], c2 = csh[2], c3 = csh[3];
    const float c4 = csh[4], c5 = csh[5], c6 = csh[6], c7 = csh[7];

    // 64 outputs per thread, kept in registers across the grid sync.
    float v[CHUNK / 256];
    float m = 0.f;
#pragma unroll
    for (int i = 0; i < CHUNK / 1024; ++i) {      // 16 groups of float4
        const int j = i * 1024 + tid * 4;
        const float* p = smem + HALO + j;
#pragma unroll
        for (int k = 0; k < 4; ++k) {
            float wet = 0.f;
            wet = fmaf(c0, p[k - D0], wet);
            wet = fmaf(c1, p[k - D1], wet);
            wet = fmaf(c2, p[k - D2], wet);
            wet = fmaf(c3, p[k - D3], wet);
            wet = fmaf(c4, p[k - D4], wet);
            wet = fmaf(c5, p[k - D5], wet);
            wet = fmaf(c6, p[k - D6], wet);
            wet = fmaf(c7, p[k - D7], wet);
            float o = fmaf(0.5f, wet, 0.5f * p[k]);
            v[i * 4 + k] = o;
            m = fmaxf(m, fabsf(o));
        }
    }

    // block max -> per-block slot (plain agent-scope atomic store; no init needed)
#pragma unroll
    for (int off = 32; off > 0; off >>= 1) m = fmaxf(m, __shfl_down(m, off, 64));
    if ((tid & 63) == 0) wmax[tid >> 6] = m;
    __syncthreads();
    if (tid == 0) {
        float bm = fmaxf(fmaxf(wmax[0], wmax[1]), fmaxf(wmax[2], wmax[3]));
        __hip_atomic_store(wsf + blk, bm, __ATOMIC_RELEASE, __HIP_MEMORY_SCOPE_AGENT);
    }

    cg::this_grid().sync();

    // every block reduces the 512 slots (2 KB) to the global max
    float a = __hip_atomic_load(wsf + tid,       __ATOMIC_ACQUIRE, __HIP_MEMORY_SCOPE_AGENT);
    float b = __hip_atomic_load(wsf + tid + 256, __ATOMIC_ACQUIRE, __HIP_MEMORY_SCOPE_AGENT);
    float mm = fmaxf(a, b);
#pragma unroll
    for (int off = 32; off > 0; off >>= 1) mm = fmaxf(mm, __shfl_down(mm, off, 64));
    if ((tid & 63) == 0) wmax[tid >> 6] = mm;
    __syncthreads();
    if (tid == 0)
        sinv = 1.0f / fmaxf(fmaxf(wmax[0], wmax[1]), fmaxf(wmax[2], wmax[3]));
    __syncthreads();
    const float inv = sinv;

    // scale registers, write coalesced float4
    const int base = blk * CHUNK;
#pragma unroll
    for (int i = 0; i < CHUNK / 1024; ++i) {
        const int j = i * 1024 + tid * 4;
        float4 ov = make_float4(v[i * 4 + 0] * inv, v[i * 4 + 1] * inv,
                                v[i * 4 + 2] * inv, v[i * 4 + 3] * inv);
        *(float4*)(out + base + j) = ov;
    }
}

extern "C" void kernel_launch(void* const* d_in, const int* in_sizes, int n_in,
                              void* d_out, int out_size, void* d_ws, size_t ws_size,
                              hipStream_t stream) {
    const float* x = (const float*)d_in[0];       // input_sig [1, T]
    const float* g = (const float*)d_in[1];       // feedback_gain [8]
    const float* Q = (const float*)d_in[2];       // orthogonal_matrix [8,8]
    float* out = (float*)d_out;
    float* wsf = (float*)d_ws;                    // 512 per-block max slots

    void* args[] = {(void*)&x, (void*)&g, (void*)&Q, (void*)&out, (void*)&wsf};
    hipLaunchCooperativeKernel((const void*)fdn_fused, dim3(NBLK), dim3(256),
                               args, 0, stream);
}